// Round 13
// baseline (160.036 us; speedup 1.0000x reference)
//
#include <hip/hip_runtime.h>
#include <math.h>

#define NPOS 2304   // 48*48
#define CC   256    // DIM
#define DI   512    // HEADS*DIM_HEAD
#define NT   36     // NPOS/64
#define SCALE 0.125f
#define MASKV -100.0f
// exp(-SCALE*sqrt(d2)) = exp2(-SCALE*log2(e)*sqrt(d2))
#define NEGSL2E (-0.18033688011112042f)

typedef __attribute__((ext_vector_type(8))) short bf16x8;  // 8 bf16 (4 VGPRs)
typedef __attribute__((ext_vector_type(4))) float f32x4;   // MFMA C/D frag
typedef unsigned short u16;
typedef unsigned int u32;

__device__ inline u16 f2bf(float f) {
    union { float f; unsigned int u; } v; v.f = f;
    return (u16)((v.u + 0x7fffu + ((v.u >> 16) & 1u)) >> 16);
}
__device__ inline float bf2f(u16 h) { return __uint_as_float(((u32)h) << 16); }

// assemble a bf16x8 frag from 8-byte-aligned LDS via two b64 reads
__device__ inline bf16x8 ld_x8(const u16* p) {
    union { bf16x8 v; uint2 d[2]; } u;
    u.d[0] = *(const uint2*)(p + 0);
    u.d[1] = *(const uint2*)(p + 4);
    return u.v;
}

// async global->LDS DMA, 16B per lane (dest = wave-uniform base + lane*16)
__device__ __forceinline__ void gl16(const u16* g, u16* l) {
    __builtin_amdgcn_global_load_lds(
        (const __attribute__((address_space(1))) void*)g,
        (__attribute__((address_space(3))) void*)l, 16, 0, 0);
}

// ---------------- Kernel 0: fused one-time prep (rmsnorm + weight convert) ----------------
// Blocks 0..71: rmsnorm once per (b,n0) -> Xn bf16. Blocks 72..455: weight
// conversion.
__global__ __launch_bounds__(256) void k_pre(const float* __restrict__ fmap,
                                             const float* __restrict__ gamma,
                                             const float* __restrict__ wqk,
                                             const float* __restrict__ wv,
                                             const float* __restrict__ wout,
                                             u16* __restrict__ xn,
                                             u16* __restrict__ wqkh,
                                             u16* __restrict__ wvh,
                                             u16* __restrict__ wo_hi,
                                             u16* __restrict__ wo_lo) {
    const int blk = blockIdx.x;            // 456
    const int t = threadIdx.x;
    if (blk >= 72) {
        const int idx = blk - 72;          // 0..383
        if (idx < 128) {                   // wqk -> bf16 (32768 float4)
            const int k = idx * 256 + t;
            const float4 v = ((const float4*)wqk)[k];
            ushort4 h4;
            h4.x = f2bf(v.x); h4.y = f2bf(v.y); h4.z = f2bf(v.z); h4.w = f2bf(v.w);
            ((ushort4*)wqkh)[k] = h4;
        } else if (idx < 256) {            // wv -> bf16
            const int k = (idx - 128) * 256 + t;
            const float4 v = ((const float4*)wv)[k];
            ushort4 h4;
            h4.x = f2bf(v.x); h4.y = f2bf(v.y); h4.z = f2bf(v.z); h4.w = f2bf(v.w);
            ((ushort4*)wvh)[k] = h4;
        } else {                           // wout -> hi/lo split
            const int k = (idx - 256) * 256 + t;
            const float4 v = ((const float4*)wout)[k];
            ushort4 h4, l4;
            h4.x = f2bf(v.x); l4.x = f2bf(v.x - bf2f(h4.x));
            h4.y = f2bf(v.y); l4.y = f2bf(v.y - bf2f(h4.y));
            h4.z = f2bf(v.z); l4.z = f2bf(v.z - bf2f(h4.z));
            h4.w = f2bf(v.w); l4.w = f2bf(v.w - bf2f(h4.w));
            ((ushort4*)wo_hi)[k] = h4;
            ((ushort4*)wo_lo)[k] = l4;
        }
        return;
    }
    // ---- rmsnorm for (b, n0): EXACT replica of the original phase A ----
    const int b = blk & 1, n0 = (blk >> 1) * 64;
    const int tx = t & 63, ty = t >> 6;
    __shared__ u16 X[64][260];             // [pos][chan]; rows 8B-aligned
    __shared__ float red[4][64];
    __shared__ float inv_s[64];
    __shared__ float gs[256];

    gs[t] = gamma[t];
    const float* fb = fmap + (size_t)b * CC * NPOS;
    float v64[64];
#pragma unroll
    for (int i = 0; i < 64; ++i)
        v64[i] = fb[(ty * 64 + i) * NPOS + n0 + tx];
    float s = 0.0f;
#pragma unroll
    for (int i = 0; i < 64; ++i) s += v64[i] * v64[i];
    red[ty][tx] = s;
    __syncthreads();
    if (t < 64) {
        const float tt = red[0][t] + red[1][t] + red[2][t] + red[3][t];
        inv_s[t] = 16.0f / fmaxf(sqrtf(tt), 1e-12f);
    }
    __syncthreads();
    const float iv = inv_s[tx];
#pragma unroll
    for (int i = 0; i < 64; i += 2) {
        const int c = ty * 64 + i;
        const float v0 = v64[i] * iv * gs[c];
        const float v1 = v64[i + 1] * iv * gs[c + 1];
        *(u32*)&X[tx][c] = (u32)f2bf(v0) | ((u32)f2bf(v1) << 16);
    }
    __syncthreads();
    // coalesced write-out: 2048 granules of 16B = full 64x256 u16 tile (32 KB)
    u16* xb = xn + ((size_t)b * NPOS + n0) * 256;
#pragma unroll
    for (int k = 0; k < 8; ++k) {
        const int gran = k * 256 + t;      // 16B granule index in the 32KB tile
        const int row = gran >> 5, colg = gran & 31;
        const uint2 lo = *(const uint2*)&X[row][colg * 8];
        const uint2 hi = *(const uint2*)&X[row][colg * 8 + 4];
        *(uint4*)&xb[(size_t)gran * 8] = make_uint4(lo.x, lo.y, hi.x, hi.y);
    }
}

// ---------------- Kernel 1: qk/v MFMA projection, head-split (Xn staged via DMA) ----------------
// Blocks 0..575 compute the qk head (epi 1), 576..1151 the v head (epi 2).
__global__ __launch_bounds__(256) void k_proj(const u16* __restrict__ xn,
                                              const u16* __restrict__ wqkh,
                                              const u16* __restrict__ wvh,
                                              const float* __restrict__ null_kv,
                                              u16* __restrict__ qkh,
                                              u16* __restrict__ vt,
                                              float* __restrict__ sq,
                                              float* __restrict__ ndot,
                                              float* __restrict__ nk2b) {
    const int blk0 = blockIdx.x;          // 0..1151
    const int isv = blk0 >= 576;
    const int blk = isv ? blk0 - 576 : blk0;
    const int xcd = blk & 7;
    const int r   = blk >> 3;             // 0..71
    const int bh  = xcd * 2 + (r & 1);    // 0..15
    const int b   = bh >> 3;
    const int oy  = bh & 7;               // head
    const int n0  = (r >> 1) * 64;        // 36 position tiles

    const int t  = threadIdx.x;
    const int w = t >> 6, lane = t & 63, mcol = lane & 15, quad = lane >> 4;

    __shared__ __align__(16) u16 Xl[16384];   // [64][256] linear, 32 KB
    __shared__ float sqp[4][64], ndp[4][64];
    u16 (*Tt)[68] = (u16(*)[68])Xl;           // aliased after phase B

    // ---- stage Xn tile: 8 rounds x 4 waves x 2 rows (1KB per gl16) ----
    const u16* xg = xn + ((size_t)b * NPOS + n0) * 256;
    {
        const int r01 = lane >> 5;            // 0/1 within the 2-row chunk
        const int jg = lane & 31;             // 16B granule in row
#pragma unroll
        for (int rr = 0; rr < 8; ++rr) {
            const int row = rr * 8 + w * 2 + r01;
            gl16(xg + (size_t)row * 256 + (size_t)((jg ^ (row & 7)) * 8),
                 Xl + (rr * 8 + w * 2) * 256);
        }
    }
    if (blk0 == 0 && t < 8) {
        float s2 = 0.0f;
#pragma unroll 8
        for (int d = 0; d < 64; ++d) { const float x = null_kv[t * 64 + d]; s2 += x * x; }
        nk2b[t] = s2;
    }
    __syncthreads();   // vmcnt(0) drain -> Xl staged

    // ---- phase B: single-head MFMA (qk or v depending on block half) ----
    const size_t wroff = (size_t)(oy * 64 + w * 16 + mcol) * 256 + quad * 8;
    const u16* wr = (isv ? wvh : wqkh) + wroff;

    f32x4 cc[4];
#pragma unroll
    for (int nf = 0; nf < 4; ++nf) cc[nf] = (f32x4){0.f, 0.f, 0.f, 0.f};
#pragma unroll
    for (int kc = 0; kc < 8; ++kc) {
        const bf16x8 aw = *(const bf16x8*)&wr[kc * 32];
        bf16x8 xB[4];
#pragma unroll
        for (int nf = 0; nf < 4; ++nf) {
            const int row = nf * 16 + mcol;
            const int g = (kc * 4 + quad) ^ (row & 7);
            xB[nf] = *(const bf16x8*)&Xl[row * 256 + g * 8];
        }
#pragma unroll
        for (int nf = 0; nf < 4; ++nf)
            cc[nf] = __builtin_amdgcn_mfma_f32_16x16x32_bf16(aw, xB[nf], cc[nf], 0, 0, 0);
    }
    __syncthreads();   // all Xl reads done; Tt alias safe

    if (!isv) {
        // ---- epilogue 1: qk head -> qkh + sq/ndot ----
        const int h = oy;   // d = w*16 + quad*4 + r, n = n0 + nf*16 + mcol
        const float4 nk4 = *(const float4*)&null_kv[h * 64 + w * 16 + quad * 4];
        float sv[4], nd[4];
#pragma unroll
        for (int nf = 0; nf < 4; ++nf) {
            sv[nf] = cc[nf][0] * cc[nf][0] + cc[nf][1] * cc[nf][1] + cc[nf][2] * cc[nf][2] + cc[nf][3] * cc[nf][3];
            nd[nf] = cc[nf][0] * nk4.x + cc[nf][1] * nk4.y + cc[nf][2] * nk4.z + cc[nf][3] * nk4.w;
        }
#pragma unroll
        for (int mk = 16; mk <= 32; mk <<= 1)
#pragma unroll
            for (int nf = 0; nf < 4; ++nf) {
                sv[nf] += __shfl_xor(sv[nf], mk);
                nd[nf] += __shfl_xor(nd[nf], mk);
            }
        if (quad == 0) {
#pragma unroll
            for (int nf = 0; nf < 4; ++nf) {
                sqp[w][nf * 16 + mcol] = sv[nf];
                ndp[w][nf * 16 + mcol] = nd[nf];
            }
        }
#pragma unroll
        for (int nf = 0; nf < 4; ++nf) {
            ushort4 r4;
            r4.x = f2bf(cc[nf][0]); r4.y = f2bf(cc[nf][1]);
            r4.z = f2bf(cc[nf][2]); r4.w = f2bf(cc[nf][3]);
            *(ushort4*)&Tt[nf * 16 + mcol][w * 16 + quad * 4] = r4;   // Tt[n][d]
        }
        __syncthreads();
        {
            const int n = t >> 2, ds = (t & 3) * 16;
            const uint2 r0 = *(const uint2*)&Tt[n][ds + 0];
            const uint2 r1 = *(const uint2*)&Tt[n][ds + 4];
            const uint2 r2 = *(const uint2*)&Tt[n][ds + 8];
            const uint2 r3 = *(const uint2*)&Tt[n][ds + 12];
            u16* dst = qkh + (((size_t)bh) * NPOS + n0 + n) * 64 + ds;
            *(uint4*)&dst[0] = make_uint4(r0.x, r0.y, r1.x, r1.y);
            *(uint4*)&dst[8] = make_uint4(r2.x, r2.y, r3.x, r3.y);
        }
        if (t < 64) {
            sq  [((size_t)bh) * NPOS + n0 + t] = sqp[0][t] + sqp[1][t] + sqp[2][t] + sqp[3][t];
            ndot[((size_t)bh) * NPOS + n0 + t] = ndp[0][t] + ndp[1][t] + ndp[2][t] + ndp[3][t];
        }
    } else {
        // ---- epilogue 2: v head -> vt frag-ordered ----
#pragma unroll
        for (int nf = 0; nf < 4; ++nf)
#pragma unroll
            for (int rr = 0; rr < 4; ++rr)
                Tt[w * 16 + quad * 4 + rr][nf * 16 + mcol] = f2bf(cc[nf][rr]);  // Tt[d][key]
        __syncthreads();
        {
            const int d = t >> 2, ks = t & 3;
            const uint2 a0 = *(const uint2*)&Tt[d][ks * 16 + 0];
            const uint2 a1 = *(const uint2*)&Tt[d][ks * 16 + 4];
            const uint2 a2 = *(const uint2*)&Tt[d][ks * 16 + 8];
            const uint2 a3 = *(const uint2*)&Tt[d][ks * 16 + 12];
            u16* vdst = vt + (size_t)bh * (72 * 64 * 32);
            const int kb = (n0 >> 5) + (ks >> 1);
            u16* p = &vdst[((size_t)kb * 64 + d) * 32 + (ks & 1) * 16];
            *(uint4*)&p[0] = make_uint4(a0.x, a0.y, a1.x, a1.y);
            *(uint4*)&p[8] = make_uint4(a2.x, a2.y, a3.x, a3.y);
        }
    }
}

// ---------------- Kernel 2: LDS-staged flash attention, in-register P transpose ----------------
// R25: Pt LDS buffer (8 KB) removed. R10 showed the 4th block never became
// resident at the zero-slack 40,960 B fit; LDS is now K(2x8K)+V(2x8K) =
// 32,768 B -> 4 blocks/CU with 32 KB slack. P transpose (QK-output layout ->
// PV A-operand layout) is an exchange purely within the 4 lanes sharing mcol
// (lanes mcol+16s): for dest quad d, bp00 word j holds keys 8d+2j,+1 =
// w[nb=d>>1][pair=j&1] from src lane mcol+16*(2(d&1)+(j>>1)); bp01 same with
// nb+2. One bpermute can't select per-dest registers (srcs serve dests with
// different nb), so each word = 2 shuffles + cndmask: 16 shfl + 8 sel per
// tile, replacing 4 ds_write + 2 ds_read + swizzle math. Values bit-identical.
template <int KS>
__global__ __launch_bounds__(256) void k_attn(const u16* __restrict__ qkh,
                                              const u16* __restrict__ vt,
                                              const float* __restrict__ null_kv,
                                              const float* __restrict__ nk2b,
                                              const float* __restrict__ sq,
                                              const float* __restrict__ ndot,
                                              u16* __restrict__ ih,
                                              u16* __restrict__ il,
                                              float* __restrict__ pO,
                                              float* __restrict__ pL) {
    const int blk = blockIdx.x;             // KS=1: 576 ; KS=2: 1152
    const int xcd = blk & 7;
    const int j = blk >> 3;
    const int bh = xcd * 2 + (j & 1);       // XCD-local bh pair
    const int r2 = j >> 1;
    const int qt = (KS == 2) ? (r2 >> 1) : r2;   // 0..35
    const int kh = (KS == 2) ? (r2 & 1) : 0;     // k-half
    const int q0 = qt * 64;
    const int b = bh >> 3, h = bh & 7;
    const int t = threadIdx.x;
    const int wave = t >> 6, lane = t & 63;
    const int mcol = lane & 15, quad = lane >> 4;

    const int kt0 = kh * 18;
    const int NTL = (KS == 2) ? 18 : 36;

    // sm (u16): [0,8192) K 2bufs x [64][64]; [8192,16384) V 2bufs. 32,768 B.
    __shared__ __align__(16) u16 sm[16384];
    u16* Kls = sm;
    u16* Vls = sm + 8192;

    const u16* qbase = qkh + (size_t)bh * NPOS * 64;
    const u16* vbase = vt + (size_t)bh * (72 * 64 * 32);
    const float* sqb = sq + (size_t)bh * NPOS;

    const int q16 = q0 + wave * 16;
    const bf16x8 bq00 = *(const bf16x8*)&qbase[(q16 + mcol) * 64 + quad * 8];
    const bf16x8 bq01 = *(const bf16x8*)&qbase[(q16 + mcol) * 64 + 32 + quad * 8];
    const float q2 = sqb[q16 + mcol];
    const int ktm = q16 >> 6;               // k-tile containing the self-masked key
    const int nbm = (q16 >> 4) & 3;

    const int kbase0 = (wave * 16 + 0) * 64;
    const int kbase1 = (wave * 16 + 8) * 64;
    const int ksrc0 = (wave * 16 + 0 + (lane >> 3)) * 64 + ((lane & 7) ^ (lane >> 3)) * 8;
    const int ksrc1 = (wave * 16 + 8 + (lane >> 3)) * 64 + ((lane & 7) ^ (lane >> 3)) * 8;
    const int vldsb = wave * 512;
    const int vsrc = (wave * 16 + (lane >> 2)) * 32 + ((lane & 3) ^ ((lane >> 3) & 3)) * 8;

    const int m7 = mcol & 7;
    const int mv = (mcol >> 1) & 3;
    // in-register P transpose lane indices (within the 4-lane mcol group)
    const int ps0 = mcol + ((quad & 1) << 5);   // mcol + 16*2*(quad&1)
    const int ps1 = ps0 + 16;
    const bool nbhi = quad >= 2;                // dest nb = quad>>1

    {   // prologue: stage tile kt0 into buf 0
        const u16* kg = qbase + (size_t)kt0 * 4096;
        const u16* vg = vbase + (size_t)kt0 * 4096;
        gl16(kg + ksrc0, Kls + kbase0);
        gl16(kg + ksrc1, Kls + kbase1);
        gl16(vg + vsrc,        Vls + vldsb);
        gl16(vg + 2048 + vsrc, Vls + 2048 + vldsb);
    }

    const bf16x8 ones = {0x3F80, 0x3F80, 0x3F80, 0x3F80, 0x3F80, 0x3F80, 0x3F80, 0x3F80};

    f32x4 oacc[4];
#pragma unroll
    for (int nb = 0; nb < 4; ++nb) oacc[nb] = (f32x4){0.f, 0.f, 0.f, 0.f};
    f32x4 lsum = (f32x4){0.f, 0.f, 0.f, 0.f};

    int p = 0;
#pragma unroll 1
    for (int i = 0; i < NTL; ++i) {
        const int kt = kt0 + i;
        __syncthreads();                    // vmcnt(0) drain -> buf[p] DMA complete
        float4 k2q[4];
#pragma unroll
        for (int nb = 0; nb < 4; ++nb)
            k2q[nb] = *(const float4*)&sqb[kt * 64 + nb * 16 + quad * 4];
        if (i + 1 < NTL) {
            const u16* kg = qbase + (size_t)(kt + 1) * 4096;
            const u16* vg = vbase + (size_t)(kt + 1) * 4096;
            const int bb = (p ^ 1) * 4096;
            gl16(kg + ksrc0, Kls + bb + kbase0);
            gl16(kg + ksrc1, Kls + bb + kbase1);
            gl16(vg + vsrc,        Vls + bb + vldsb);
            gl16(vg + 2048 + vsrc, Vls + bb + 2048 + vldsb);
        }

        const u16* Kb = Kls + p * 4096;
        const u16* Vb = Vls + p * 4096;

        bf16x8 bk[4][2];
#pragma unroll
        for (int nb = 0; nb < 4; ++nb) {
            const int rr = (nb * 16 + mcol) * 64;
            bk[nb][0] = *(const bf16x8*)&Kb[rr + ((quad ^ m7)) * 8];
            bk[nb][1] = *(const bf16x8*)&Kb[rr + (((4 + quad) ^ m7)) * 8];
        }

        f32x4 c[4];
#pragma unroll
        for (int nb = 0; nb < 4; ++nb) {
            c[nb] = (f32x4){0.f, 0.f, 0.f, 0.f};
            c[nb] = __builtin_amdgcn_mfma_f32_16x16x32_bf16(bk[nb][0], bq00, c[nb], 0, 0, 0);
            c[nb] = __builtin_amdgcn_mfma_f32_16x16x32_bf16(bk[nb][1], bq01, c[nb], 0, 0, 0);
        }

        bf16x8 bv[4][2];
#pragma unroll
        for (int nb = 0; nb < 4; ++nb) {
            const int rr = (nb * 16 + mcol) * 32 + ((quad ^ mv)) * 8;
            bv[nb][0] = *(const bf16x8*)&Vb[rr];
            bv[nb][1] = *(const bf16x8*)&Vb[2048 + rr];
        }

        u32 w01[4], w23[4];
#pragma unroll
        for (int nb = 0; nb < 4; ++nb) {
            float e[4];
#pragma unroll
            for (int r = 0; r < 4; ++r) {
                const float pre = q2 + ((const float*)&k2q[nb])[r];
                const float d2 = fmaxf(__builtin_fmaf(c[nb][r], -2.0f, pre), 0.0f);
                e[r] = __builtin_amdgcn_exp2f(NEGSL2E * __builtin_amdgcn_sqrtf(d2));
            }
            if (kt == ktm && nb == nbm) {
#pragma unroll
                for (int r = 0; r < 4; ++r)
                    if (quad * 4 + r == mcol) e[r] = 0.0f;   // exp(MASKV) ~ 0
            }
            w01[nb] = __builtin_amdgcn_perm(__float_as_uint(e[1]), __float_as_uint(e[0]), 0x07060302u);
            w23[nb] = __builtin_amdgcn_perm(__float_as_uint(e[3]), __float_as_uint(e[2]), 0x07060302u);
        }

        // ---- in-register P transpose (4-lane mcol group) ----
        union { bf16x8 v; u32 d[4]; } P00, P01;
        {
            const u32 a0 = __shfl(w01[0], ps0, 64), b0 = __shfl(w01[1], ps0, 64);
            const u32 a1 = __shfl(w23[0], ps0, 64), b1 = __shfl(w23[1], ps0, 64);
            const u32 a2 = __shfl(w01[0], ps1, 64), b2 = __shfl(w01[1], ps1, 64);
            const u32 a3 = __shfl(w23[0], ps1, 64), b3 = __shfl(w23[1], ps1, 64);
            P00.d[0] = nbhi ? b0 : a0;
            P00.d[1] = nbhi ? b1 : a1;
            P00.d[2] = nbhi ? b2 : a2;
            P00.d[3] = nbhi ? b3 : a3;
            const u32 c0 = __shfl(w01[2], ps0, 64), e0 = __shfl(w01[3], ps0, 64);
            const u32 c1 = __shfl(w23[2], ps0, 64), e1 = __shfl(w23[3], ps0, 64);
            const u32 c2 = __shfl(w01[2], ps1, 64), e2 = __shfl(w01[3], ps1, 64);
            const u32 c3 = __shfl(w23[2], ps1, 64), e3 = __shfl(w23[3], ps1, 64);
            P01.d[0] = nbhi ? e0 : c0;
            P01.d[1] = nbhi ? e1 : c1;
            P01.d[2] = nbhi ? e2 : c2;
            P01.d[3] = nbhi ? e3 : c3;
        }
        const bf16x8 bp00 = P00.v;
        const bf16x8 bp01 = P01.v;

#pragma unroll
        for (int nb = 0; nb < 4; ++nb) {
            oacc[nb] = __builtin_amdgcn_mfma_f32_16x16x32_bf16(bv[nb][0], bp00, oacc[nb], 0, 0, 0);
            oacc[nb] = __builtin_amdgcn_mfma_f32_16x16x32_bf16(bv[nb][1], bp01, oacc[nb], 0, 0, 0);
        }
        lsum = __builtin_amdgcn_mfma_f32_16x16x32_bf16(ones, bp00, lsum, 0, 0, 0);
        lsum = __builtin_amdgcn_mfma_f32_16x16x32_bf16(ones, bp01, lsum, 0, 0, 0);

        p ^= 1;
    }

    __syncthreads();                        // main loop done; K/V region reusable

    float* Ofin = (float*)sm + wave * (16 * 68);   // 17.4 KB < 32.77 KB
#pragma unroll
    for (int nb = 0; nb < 4; ++nb)
        *(f32x4*)&Ofin[mcol * 68 + nb * 16 + quad * 4] = oacc[nb];
    if (quad == 0) Ofin[mcol * 68 + 64] = lsum[0];

    {
        const int q = lane >> 2;            // 0..15
        const int d0 = (lane & 3) * 16;     // 0, 16, 32, 48
        const float4 a0 = *(const float4*)&Ofin[q * 68 + d0 + 0];
        const float4 a1 = *(const float4*)&Ofin[q * 68 + d0 + 4];
        const float4 a2 = *(const float4*)&Ofin[q * 68 + d0 + 8];
        const float4 a3 = *(const float4*)&Ofin[q * 68 + d0 + 12];
        const float l = Ofin[q * 68 + 64];
        const int qg = q16 + q;

        if (KS == 2) {
            float* dst = pO + (size_t)kh * 2359296 + ((size_t)bh * NPOS + qg) * 64 + d0;
            *(float4*)&dst[0]  = a0;
            *(float4*)&dst[4]  = a1;
            *(float4*)&dst[8]  = a2;
            *(float4*)&dst[12] = a3;
            if ((lane & 3) == 0)
                pL[(size_t)kh * 36864 + (size_t)bh * NPOS + qg] = l;
        } else {
            const float q2v = sqb[qg];
            const float nd = ndot[(size_t)bh * NPOS + qg];
            const float nk2 = nk2b[h];
            const float d2n = fmaxf(q2v + nk2 - 2.0f * nd, 0.0f);
            const float beta = __expf(-sqrtf(d2n) * SCALE);
            const float ilv = 1.0f / (l + beta);

            const float* nvp = &null_kv[DI + h * 64 + d0];
            const float4 nv0 = *(const float4*)&nvp[0];
            const float4 nv1 = *(const float4*)&nvp[4];
            const float4 nv2 = *(const float4*)&nvp[8];
            const float4 nv3 = *(const float4*)&nvp[12];

            const size_t ob = ((size_t)b * NPOS + qg) * DI + h * 64 + d0;
            float vv[16];
            vv[0]  = (a0.x + beta * nv0.x) * ilv; vv[1]  = (a0.y + beta * nv0.y) * ilv;
            vv[2]  = (a0.z + beta * nv0.z) * ilv; vv[3]  = (a0.w + beta * nv0.w) * ilv;
            vv[4]  = (a1.x + beta * nv1.x) * ilv; vv[5]  = (a1.y + beta * nv1.y) * ilv;
            vv[6]  = (a1.z + beta * nv1.z) * ilv; vv[7]  = (a1.w + beta * nv1.w) * ilv;
            vv[8]  = (a2.x + beta * nv2.x) * ilv; vv[9]  = (a2.y + beta * nv2.y) * ilv;
            vv[10] = (a2.z + beta * nv2.z) * ilv; vv[11] = (a2.w + beta * nv2.w) * ilv;
            vv[12] = (a3.x + beta * nv3.x) * ilv; vv[13] = (a3.y + beta * nv3.y) * ilv;
            vv[14] = (a3.z + beta * nv3.z) * ilv; vv[15] = (a3.w + beta * nv3.w) * ilv;
#pragma unroll
            for (int g = 0; g < 4; ++g) {
                ushort4 hi4, lo4;
                hi4.x = f2bf(vv[g * 4 + 0]); lo4.x = f2bf(vv[g * 4 + 0] - bf2f(hi4.x));
                hi4.y = f2bf(vv[g * 4 + 1]); lo4.y = f2bf(vv[g * 4 + 1] - bf2f(hi4.y));
                hi4.z = f2bf(vv[g * 4 + 2]); lo4.z = f2bf(vv[g * 4 + 2] - bf2f(hi4.z));
                hi4.w = f2bf(vv[g * 4 + 3]); lo4.w = f2bf(vv[g * 4 + 3] - bf2f(hi4.w));
                *(ushort4*)&ih[ob + g * 4] = hi4;
                *(ushort4*)&il[ob + g * 4] = lo4;
            }
        }
    }
}

// ---------------- Kernel 2b: merge k-split partials + beta/normalize -> ih/il ----------------
__global__ __launch_bounds__(256) void k_merge(const float* __restrict__ pO,
                                               const float* __restrict__ pL,
                                               const float* __restrict__ null_kv,
                                               const float* __restrict__ nk2b,
                                               const float* __restrict__ sq,
                                               const float* __restrict__ ndot,
                                               u16* __restrict__ ih,
                                               u16* __restrict__ il) {
    const int gid = blockIdx.x * 256 + (int)threadIdx.x;   // 0..147455
    const int d0 = (gid & 3) * 16;
    const int t2 = gid >> 2;                 // 0..36863
    const int bh = t2 / NPOS;                // 0..15
    const int qg = t2 - bh * NPOS;
    const int b = bh >> 3, h = bh & 7;

    const size_t o0 = ((size_t)bh * NPOS + qg) * 64 + d0;
    const size_t o1 = o0 + 2359296;
    const float4 a0 = *(const float4*)&pO[o0 + 0];
    const float4 a1 = *(const float4*)&pO[o0 + 4];
    const float4 a2 = *(const float4*)&pO[o0 + 8];
    const float4 a3 = *(const float4*)&pO[o0 + 12];
    const float4 c0 = *(const float4*)&pO[o1 + 0];
    const float4 c1 = *(const float4*)&pO[o1 + 4];
    const float4 c2 = *(const float4*)&pO[o1 + 8];
    const float4 c3 = *(const float4*)&pO[o1 + 12];
    const float l = pL[(size_t)bh * NPOS + qg] + pL[36864 + (size_t)bh * NPOS + qg];

    const float q2v = sq[(size_t)bh * NPOS + qg];
    const float nd = ndot[(size_t)bh * NPOS + qg];
    const float nk2 = nk2b[h];
    const float d2n = fmaxf(q2v + nk2 - 2.0f * nd, 0.0f);
    const float beta = __expf(-sqrtf(d2n) * SCALE);
    const float ilv = 1.0f / (l + beta);

    const float* nvp = &null_kv[DI + h * 64 + d0];
    const float4 nv0 = *(const float4*)&nvp[0];
    const float4 nv1 = *(const float4*)&nvp[4];
    const float4 nv2 = *(const float4*)&nvp[8];
    const float4 nv3 = *(const float4*)&nvp[12];

    float vv[16];
    vv[0]  = (a0.x + c0.x + beta * nv0.x) * ilv; vv[1]  = (a0.y + c0.y + beta * nv0.y) * ilv;
    vv[2]  = (a0.z + c0.z + beta * nv0.z) * ilv; vv[3]  = (a0.w + c0.w + beta * nv0.w) * ilv;
    vv[4]  = (a1.x + c1.x + beta * nv1.x) * ilv; vv[5]  = (a1.y + c1.y + beta * nv1.y) * ilv;
    vv[6]  = (a1.z + c1.z + beta * nv1.z) * ilv; vv[7]  = (a1.w + c1.w + beta * nv1.w) * ilv;
    vv[8]  = (a2.x + c2.x + beta * nv2.x) * ilv; vv[9]  = (a2.y + c2.y + beta * nv2.y) * ilv;
    vv[10] = (a2.z + c2.z + beta * nv2.z) * ilv; vv[11] = (a2.w + c2.w + beta * nv2.w) * ilv;
    vv[12] = (a3.x + c3.x + beta * nv3.x) * ilv; vv[13] = (a3.y + c3.y + beta * nv3.y) * ilv;
    vv[14] = (a3.z + c3.z + beta * nv3.z) * ilv; vv[15] = (a3.w + c3.w + beta * nv3.w) * ilv;

    const size_t ob = ((size_t)b * NPOS + qg) * DI + h * 64 + d0;
#pragma unroll
    for (int g = 0; g < 4; ++g) {
        ushort4 hi4, lo4;
        hi4.x = f2bf(vv[g * 4 + 0]); lo4.x = f2bf(vv[g * 4 + 0] - bf2f(hi4.x));
        hi4.y = f2bf(vv[g * 4 + 1]); lo4.y = f2bf(vv[g * 4 + 1] - bf2f(hi4.y));
        hi4.z = f2bf(vv[g * 4 + 2]); lo4.z = f2bf(vv[g * 4 + 2] - bf2f(hi4.z));
        hi4.w = f2bf(vv[g * 4 + 3]); lo4.w = f2bf(vv[g * 4 + 3] - bf2f(hi4.w));
        *(ushort4*)&ih[ob + g * 4] = hi4;
        *(ushort4*)&il[ob + g * 4] = lo4;
    }
}

// ---------------- Kernel 3: output projection, LDS-staged B (shared across waves) ----------------
__global__ __launch_bounds__(256) void k_out(const u16* __restrict__ wo_hi,
                                             const u16* __restrict__ wo_lo,
                                             const u16* __restrict__ ih,
                                             const u16* __restrict__ il,
                                             float* __restrict__ out) {
    const int j0 = blockIdx.x * 32;        // 72 j-tiles of 32 -> 576 blocks
    const int c0 = blockIdx.y * 64;
    const int b  = blockIdx.z;
    const int t  = threadIdx.x;
    const int w = t >> 6, lane = t & 63, mcol = lane & 15, quad = lane >> 4;

    // [buf][hi/lo][32 j][64 k] u16 = 16 KB
    __shared__ __align__(16) u16 Bst[2][2][32][64];

    const u16* ah = wo_hi + (size_t)(c0 + w * 16 + mcol) * 512 + quad * 8;
    const u16* al = wo_lo + (size_t)(c0 + w * 16 + mcol) * 512 + quad * 8;

    const size_t bsrc_row = (size_t)b * NPOS + j0 + w * 8 + (lane >> 3);
    const int bsg = ((lane & 7) ^ (lane >> 3)) * 8;
    const u16* bsrc_h = ih + bsrc_row * 512 + bsg;
    const u16* bsrc_l = il + bsrc_row * 512 + bsg;
    u16* bdst_h = &Bst[0][0][w * 8][0];
    u16* bdst_l = &Bst[0][1][w * 8][0];

    gl16(bsrc_h, bdst_h);                  // phase 0 -> buf 0
    gl16(bsrc_l, bdst_l);

    f32x4 c[2];
    c[0] = (f32x4){0.f, 0.f, 0.f, 0.f};
    c[1] = (f32x4){0.f, 0.f, 0.f, 0.f};

    int p = 0;
#pragma unroll 1
    for (int ph = 0; ph < 8; ++ph) {
        __syncthreads();                   // vmcnt(0) drain -> buf[p] complete
        if (ph + 1 < 8) {
            const int ko = (ph + 1) * 64;
            gl16(bsrc_h + ko, bdst_h + (p ^ 1) * 4096);
            gl16(bsrc_l + ko, bdst_l + (p ^ 1) * 4096);
        }
        const u16* Bb = &Bst[p][0][0][0];
#pragma unroll
        for (int sub = 0; sub < 2; ++sub) {
            const int kc = ph * 2 + sub;
            const bf16x8 A  = *(const bf16x8*)&ah[kc * 32];
            const bf16x8 Al = *(const bf16x8*)&al[kc * 32];
#pragma unroll
            for (int nf = 0; nf < 2; ++nf) {
                const int r = nf * 16 + mcol;
                const int g = (sub * 4 + quad) ^ (r & 7);
                const bf16x8 Bh = *(const bf16x8*)&Bb[r * 64 + g * 8];
                const bf16x8 Bl = *(const bf16x8*)&Bb[2048 + r * 64 + g * 8];
                c[nf] = __builtin_amdgcn_mfma_f32_16x16x32_bf16(A,  Bh, c[nf], 0, 0, 0);
                c[nf] = __builtin_amdgcn_mfma_f32_16x16x32_bf16(A,  Bl, c[nf], 0, 0, 0);
                c[nf] = __builtin_amdgcn_mfma_f32_16x16x32_bf16(Al, Bh, c[nf], 0, 0, 0);
            }
        }
        p ^= 1;
    }
    float* ob = out + ((size_t)b * CC + c0 + w * 16) * NPOS + j0;
#pragma unroll
    for (int nf = 0; nf < 2; ++nf)
#pragma unroll
        for (int r = 0; r < 4; ++r)
            ob[(size_t)(quad * 4 + r) * NPOS + nf * 16 + mcol] = c[nf][r];
}

extern "C" void kernel_launch(void* const* d_in, const int* in_sizes, int n_in,
                              void* d_out, int out_size, void* d_ws, size_t ws_size,
                              hipStream_t stream) {
    const float* fmap    = (const float*)d_in[0];
    const float* gamma   = (const float*)d_in[1];
    const float* w_qk    = (const float*)d_in[2];
    const float* w_v     = (const float*)d_in[3];
    const float* null_kv = (const float*)d_in[4];
    const float* w_out   = (const float*)d_in[5];
    float* out = (float*)d_out;

    u16* ws16 = (u16*)d_ws;
    u16* qkh    = ws16;                     // 16*2304*64  = 2,359,296 u16
    u16* vtb    = qkh + 2359296;            // 16*72*64*32 = 2,359,296
    u16* in_hi  = vtb + 2359296;            // 2*2304*512  = 2,359,296
    u16* in_lo  = in_hi + 2359296;          //               2,359,296
    u16* wo_hi  = in_lo + 2359296;          // 256*512     =   131,072
    u16* wo_lo  = wo_hi + 131072;           //                 131,072
    u16* wqkh   = wo_lo + 131072;           // 512*256     =   131,072
    u16* wvh    = wqkh + 131072;            //                 131,072
    u16* xnb    = wvh + 131072;             // 2*2304*256  = 1,179,648
    float* sqbuf = (float*)(xnb + 1179648);     // 36,864 f32
    float* ndbuf = sqbuf + 36864;               // 36,864
    float* nk2b  = ndbuf + 36864;               // 8
    // base total ~22.6 MB; k-split partials below need +19.2 MB
    float* pOws  = nk2b + 8;                    // 2*16*2304*64 = 4,718,592 f32
    float* pLws  = pOws + 4718592;              // 2*16*2304    =    73,728 f32
    const size_t need_split = (size_t)((char*)(pLws + 73728) - (char*)d_ws);
    const bool split = (ws_size >= need_split);

    hipLaunchKernelGGL(k_pre,  dim3(456),       dim3(256), 0, stream,
                       fmap, gamma, w_qk, w_v, w_out, xnb, wqkh, wvh, wo_hi, wo_lo);
    hipLaunchKernelGGL(k_proj, dim3(1152),      dim3(256), 0, stream,
                       xnb, wqkh, wvh, null_kv, qkh, vtb, sqbuf, ndbuf, nk2b);
    if (split) {
        hipLaunchKernelGGL(HIP_KERNEL_NAME(k_attn<2>), dim3(1152), dim3(256), 0, stream,
                           qkh, vtb, null_kv, nk2b, sqbuf, ndbuf, in_hi, in_lo, pOws, pLws);
        hipLaunchKernelGGL(k_merge, dim3(576),  dim3(256), 0, stream,
                           pOws, pLws, null_kv, nk2b, sqbuf, ndbuf, in_hi, in_lo);
    } else {
        hipLaunchKernelGGL(HIP_KERNEL_NAME(k_attn<1>), dim3(576), dim3(256), 0, stream,
                           qkh, vtb, null_kv, nk2b, sqbuf, ndbuf, in_hi, in_lo, pOws, pLws);
    }
    hipLaunchKernelGGL(k_out,  dim3(72, 4, 2),  dim3(256), 0, stream,
                       wo_hi, wo_lo, in_hi, in_lo, out);
}

// Round 14
// 155.238 us; speedup vs baseline: 1.0309x; 1.0309x over previous
//
#include <hip/hip_runtime.h>
#include <math.h>

#define NPOS 2304   // 48*48
#define CC   256    // DIM
#define DI   512    // HEADS*DIM_HEAD
#define NT   36     // NPOS/64
#define SCALE 0.125f
#define MASKV -100.0f
// exp(-SCALE*sqrt(d2)) = exp2(-SCALE*log2(e)*sqrt(d2))
#define NEGSL2E (-0.18033688011112042f)

typedef __attribute__((ext_vector_type(8))) short bf16x8;  // 8 bf16 (4 VGPRs)
typedef __attribute__((ext_vector_type(4))) float f32x4;   // MFMA C/D frag
typedef unsigned short u16;
typedef unsigned int u32;

__device__ inline u16 f2bf(float f) {
    union { float f; unsigned int u; } v; v.f = f;
    return (u16)((v.u + 0x7fffu + ((v.u >> 16) & 1u)) >> 16);
}
__device__ inline float bf2f(u16 h) { return __uint_as_float(((u32)h) << 16); }

// assemble a bf16x8 frag from 8-byte-aligned LDS via two b64 reads
__device__ inline bf16x8 ld_x8(const u16* p) {
    union { bf16x8 v; uint2 d[2]; } u;
    u.d[0] = *(const uint2*)(p + 0);
    u.d[1] = *(const uint2*)(p + 4);
    return u.v;
}

// async global->LDS DMA, 16B per lane (dest = wave-uniform base + lane*16)
__device__ __forceinline__ void gl16(const u16* g, u16* l) {
    __builtin_amdgcn_global_load_lds(
        (const __attribute__((address_space(1))) void*)g,
        (__attribute__((address_space(3))) void*)l, 16, 0, 0);
}

// ---------------- Kernel 0: one-time weight prep ----------------
// R26: restore of the best-measured config (R7, 155.7 µs). Weight conversion
// done once here; k_proj keeps phase A fused (R9's rmsnorm split and R12's
// head-split were both neutral; R13's shuffle-transpose regressed because
// __shfl = ds_bpermute on CDNA -> MORE LDS-pipe work on the critical path).
__global__ __launch_bounds__(256) void k_prep(const float* __restrict__ wqk,
                                              const float* __restrict__ wv,
                                              const float* __restrict__ wout,
                                              u16* __restrict__ wqkh,
                                              u16* __restrict__ wvh,
                                              u16* __restrict__ wo_hi,
                                              u16* __restrict__ wo_lo) {
    const int blk = blockIdx.x;            // 384
    const int t = threadIdx.x;
    if (blk < 128) {                       // wqk -> bf16 (32768 float4)
        const int k = blk * 256 + t;
        const float4 v = ((const float4*)wqk)[k];
        ushort4 h4;
        h4.x = f2bf(v.x); h4.y = f2bf(v.y); h4.z = f2bf(v.z); h4.w = f2bf(v.w);
        ((ushort4*)wqkh)[k] = h4;
    } else if (blk < 256) {                // wv -> bf16
        const int k = (blk - 128) * 256 + t;
        const float4 v = ((const float4*)wv)[k];
        ushort4 h4;
        h4.x = f2bf(v.x); h4.y = f2bf(v.y); h4.z = f2bf(v.z); h4.w = f2bf(v.w);
        ((ushort4*)wvh)[k] = h4;
    } else {                               // wout -> hi/lo split
        const int k = (blk - 256) * 256 + t;
        const float4 v = ((const float4*)wout)[k];
        ushort4 h4, l4;
        h4.x = f2bf(v.x); l4.x = f2bf(v.x - bf2f(h4.x));
        h4.y = f2bf(v.y); l4.y = f2bf(v.y - bf2f(h4.y));
        h4.z = f2bf(v.z); l4.z = f2bf(v.z - bf2f(h4.z));
        h4.w = f2bf(v.w); l4.w = f2bf(v.w - bf2f(h4.w));
        ((ushort4*)wo_hi)[k] = h4;
        ((ushort4*)wo_lo)[k] = l4;
    }
}

// ---------------- Kernel 1: fused rmsnorm + paired qk/v MFMA projection ----------------
// XCD-aligned 1D grid (576): xcd=blk&7 produces bh=xcd*2+(r&1), matching
// k_attn's consumer swizzle. Weights arrive pre-converted bf16 (k_prep).
__global__ __launch_bounds__(256) void k_proj(const float* __restrict__ fmap,
                                              const float* __restrict__ gamma,
                                              const u16* __restrict__ wqkh,
                                              const u16* __restrict__ wvh,
                                              const float* __restrict__ null_kv,
                                              u16* __restrict__ qkh,
                                              u16* __restrict__ vt,
                                              float* __restrict__ sq,
                                              float* __restrict__ ndot,
                                              float* __restrict__ nk2b) {
    const int blk = blockIdx.x;
    const int xcd = blk & 7;
    const int r   = blk >> 3;             // 0..71
    const int bh  = xcd * 2 + (r & 1);    // 0..15
    const int b   = bh >> 3;
    const int oy  = bh & 7;               // head
    const int n0  = (r >> 1) * 64;        // 36 position tiles

    const int t  = threadIdx.x;
    const int w = t >> 6, lane = t & 63, mcol = lane & 15, quad = lane >> 4;
    const int tx = t & 63, ty = t >> 6;

    __shared__ u16 X[64][260];            // [pos][chan]; dword pitch 130, rows 8B-aligned
    __shared__ float red[4][64];
    __shared__ float inv_s[64];
    __shared__ float gs[256];
    __shared__ float sqp[4][64], ndp[4][64];
    u16 (*Tt)[68] = (u16(*)[68])X;        // aliased after phase B

    // ---- phase A: rmsnorm, fmap held in registers (single global pass) ----
    gs[t] = gamma[t];
    const float* fb = fmap + (size_t)b * CC * NPOS;
    float v64[64];
#pragma unroll
    for (int i = 0; i < 64; ++i)
        v64[i] = fb[(ty * 64 + i) * NPOS + n0 + tx];
    float s = 0.0f;
#pragma unroll
    for (int i = 0; i < 64; ++i) s += v64[i] * v64[i];
    red[ty][tx] = s;
    __syncthreads();
    if (t < 64) {
        const float tt = red[0][t] + red[1][t] + red[2][t] + red[3][t];
        inv_s[t] = 16.0f / fmaxf(sqrtf(tt), 1e-12f);
    }
    __syncthreads();
    const float iv = inv_s[tx];
#pragma unroll
    for (int i = 0; i < 64; i += 2) {
        const int c = ty * 64 + i;
        const float v0 = v64[i] * iv * gs[c];
        const float v1 = v64[i + 1] * iv * gs[c + 1];
        *(u32*)&X[tx][c] = (u32)f2bf(v0) | ((u32)f2bf(v1) << 16);   // bank 2-way: free
    }
    if (blk == 0 && t < 8) {
        float s2 = 0.0f;
#pragma unroll 8
        for (int d = 0; d < 64; ++d) { const float x = null_kv[t * 64 + d]; s2 += x * x; }
        nk2b[t] = s2;
    }
    __syncthreads();

    // ---- phase B (dual): one X frag read feeds qk-head AND v-head MFMA ----
    const size_t wroff = (size_t)(oy * 64 + w * 16 + mcol) * 256 + quad * 8;
    const u16* wrq = wqkh + wroff;
    const u16* wrv = wvh + wroff;

    f32x4 cq[4], cv[4];
#pragma unroll
    for (int nf = 0; nf < 4; ++nf) {
        cq[nf] = (f32x4){0.f, 0.f, 0.f, 0.f};
        cv[nf] = (f32x4){0.f, 0.f, 0.f, 0.f};
    }
#pragma unroll
    for (int kc = 0; kc < 8; ++kc) {
        const bf16x8 aq = *(const bf16x8*)&wrq[kc * 32];
        const bf16x8 av = *(const bf16x8*)&wrv[kc * 32];
        bf16x8 xB[4];
#pragma unroll
        for (int nf = 0; nf < 4; ++nf)
            xB[nf] = ld_x8(&X[nf * 16 + mcol][kc * 32 + quad * 8]);
#pragma unroll
        for (int nf = 0; nf < 4; ++nf) {
            cq[nf] = __builtin_amdgcn_mfma_f32_16x16x32_bf16(aq, xB[nf], cq[nf], 0, 0, 0);
            cv[nf] = __builtin_amdgcn_mfma_f32_16x16x32_bf16(av, xB[nf], cv[nf], 0, 0, 0);
        }
    }
    __syncthreads();   // all X reads done; Tt alias safe

    // ---- epilogue 1: qk head -> qkh + sq/ndot ----
    {
        const int h = oy;   // d = w*16 + quad*4 + r, n = n0 + nf*16 + mcol
        const float4 nk4 = *(const float4*)&null_kv[h * 64 + w * 16 + quad * 4];
        float sv[4], nd[4];
#pragma unroll
        for (int nf = 0; nf < 4; ++nf) {
            sv[nf] = cq[nf][0] * cq[nf][0] + cq[nf][1] * cq[nf][1] + cq[nf][2] * cq[nf][2] + cq[nf][3] * cq[nf][3];
            nd[nf] = cq[nf][0] * nk4.x + cq[nf][1] * nk4.y + cq[nf][2] * nk4.z + cq[nf][3] * nk4.w;
        }
#pragma unroll
        for (int mk = 16; mk <= 32; mk <<= 1)
#pragma unroll
            for (int nf = 0; nf < 4; ++nf) {
                sv[nf] += __shfl_xor(sv[nf], mk);
                nd[nf] += __shfl_xor(nd[nf], mk);
            }
        if (quad == 0) {
#pragma unroll
            for (int nf = 0; nf < 4; ++nf) {
                sqp[w][nf * 16 + mcol] = sv[nf];
                ndp[w][nf * 16 + mcol] = nd[nf];
            }
        }
#pragma unroll
        for (int nf = 0; nf < 4; ++nf) {
            ushort4 r4;
            r4.x = f2bf(cq[nf][0]); r4.y = f2bf(cq[nf][1]);
            r4.z = f2bf(cq[nf][2]); r4.w = f2bf(cq[nf][3]);
            *(ushort4*)&Tt[nf * 16 + mcol][w * 16 + quad * 4] = r4;   // Tt[n][d]
        }
        __syncthreads();
        {
            const int n = t >> 2, ds = (t & 3) * 16;
            const uint2 r0 = *(const uint2*)&Tt[n][ds + 0];
            const uint2 r1 = *(const uint2*)&Tt[n][ds + 4];
            const uint2 r2 = *(const uint2*)&Tt[n][ds + 8];
            const uint2 r3 = *(const uint2*)&Tt[n][ds + 12];
            u16* dst = qkh + (((size_t)bh) * NPOS + n0 + n) * 64 + ds;
            *(uint4*)&dst[0] = make_uint4(r0.x, r0.y, r1.x, r1.y);
            *(uint4*)&dst[8] = make_uint4(r2.x, r2.y, r3.x, r3.y);
        }
        if (t < 64) {
            sq  [((size_t)bh) * NPOS + n0 + t] = sqp[0][t] + sqp[1][t] + sqp[2][t] + sqp[3][t];
            ndot[((size_t)bh) * NPOS + n0 + t] = ndp[0][t] + ndp[1][t] + ndp[2][t] + ndp[3][t];
        }
    }
    __syncthreads();   // qk readback done before Tt reuse

    // ---- epilogue 2: v head -> vt frag-ordered ----
    {
#pragma unroll
        for (int nf = 0; nf < 4; ++nf)
#pragma unroll
            for (int rr = 0; rr < 4; ++rr)
                Tt[w * 16 + quad * 4 + rr][nf * 16 + mcol] = f2bf(cv[nf][rr]);  // Tt[d][key]
        __syncthreads();
        {
            const int d = t >> 2, ks = t & 3;
            const uint2 a0 = *(const uint2*)&Tt[d][ks * 16 + 0];
            const uint2 a1 = *(const uint2*)&Tt[d][ks * 16 + 4];
            const uint2 a2 = *(const uint2*)&Tt[d][ks * 16 + 8];
            const uint2 a3 = *(const uint2*)&Tt[d][ks * 16 + 12];
            u16* vdst = vt + (size_t)bh * (72 * 64 * 32);
            const int kb = (n0 >> 5) + (ks >> 1);
            u16* p = &vdst[((size_t)kb * 64 + d) * 32 + (ks & 1) * 16];
            *(uint4*)&p[0] = make_uint4(a0.x, a0.y, a1.x, a1.y);
            *(uint4*)&p[8] = make_uint4(a2.x, a2.y, a3.x, a3.y);
        }
    }
}

// ---------------- Kernel 2: LDS-staged flash attention, 64 q/block, async DMA staging ----------------
// KS=2 k-split (grid 1152), gl16 staging with both-sides XOR swizzle,
// Pt[72] LDS transpose. KS=1 fallback when workspace too small.
template <int KS>
__global__ __launch_bounds__(256) void k_attn(const u16* __restrict__ qkh,
                                              const u16* __restrict__ vt,
                                              const float* __restrict__ null_kv,
                                              const float* __restrict__ nk2b,
                                              const float* __restrict__ sq,
                                              const float* __restrict__ ndot,
                                              u16* __restrict__ ih,
                                              u16* __restrict__ il,
                                              float* __restrict__ pO,
                                              float* __restrict__ pL) {
    const int blk = blockIdx.x;             // KS=1: 576 ; KS=2: 1152
    const int xcd = blk & 7;
    const int j = blk >> 3;
    const int bh = xcd * 2 + (j & 1);       // XCD-local bh pair
    const int r2 = j >> 1;
    const int qt = (KS == 2) ? (r2 >> 1) : r2;   // 0..35
    const int kh = (KS == 2) ? (r2 & 1) : 0;     // k-half
    const int q0 = qt * 64;
    const int b = bh >> 3, h = bh & 7;
    const int t = threadIdx.x;
    const int wave = t >> 6, lane = t & 63;
    const int mcol = lane & 15, quad = lane >> 4;

    const int kt0 = kh * 18;
    const int NTL = (KS == 2) ? 18 : 36;

    __shared__ __align__(16) u16 sm[20992];
    u16* Kls = sm;
    u16* Vls = sm + 8192;
    u16 (*Pt)[72] = (u16(*)[72])(sm + 16384 + wave * 1152);

    const u16* qbase = qkh + (size_t)bh * NPOS * 64;
    const u16* vbase = vt + (size_t)bh * (72 * 64 * 32);
    const float* sqb = sq + (size_t)bh * NPOS;

    const int q16 = q0 + wave * 16;
    const bf16x8 bq00 = *(const bf16x8*)&qbase[(q16 + mcol) * 64 + quad * 8];
    const bf16x8 bq01 = *(const bf16x8*)&qbase[(q16 + mcol) * 64 + 32 + quad * 8];
    const float q2 = sqb[q16 + mcol];
    const int ktm = q16 >> 6;               // k-tile containing the self-masked key
    const int nbm = (q16 >> 4) & 3;

    const int kbase0 = (wave * 16 + 0) * 64;
    const int kbase1 = (wave * 16 + 8) * 64;
    const int ksrc0 = (wave * 16 + 0 + (lane >> 3)) * 64 + ((lane & 7) ^ (lane >> 3)) * 8;
    const int ksrc1 = (wave * 16 + 8 + (lane >> 3)) * 64 + ((lane & 7) ^ (lane >> 3)) * 8;
    const int vldsb = wave * 512;
    const int vsrc = (wave * 16 + (lane >> 2)) * 32 + ((lane & 3) ^ ((lane >> 3) & 3)) * 8;

    const int m7 = mcol & 7;
    const int mv = (mcol >> 1) & 3;

    {   // prologue: stage tile kt0 into buf 0
        const u16* kg = qbase + (size_t)kt0 * 4096;
        const u16* vg = vbase + (size_t)kt0 * 4096;
        gl16(kg + ksrc0, Kls + kbase0);
        gl16(kg + ksrc1, Kls + kbase1);
        gl16(vg + vsrc,        Vls + vldsb);
        gl16(vg + 2048 + vsrc, Vls + 2048 + vldsb);
    }

    const bf16x8 ones = {0x3F80, 0x3F80, 0x3F80, 0x3F80, 0x3F80, 0x3F80, 0x3F80, 0x3F80};

    f32x4 oacc[4];
#pragma unroll
    for (int nb = 0; nb < 4; ++nb) oacc[nb] = (f32x4){0.f, 0.f, 0.f, 0.f};
    f32x4 lsum = (f32x4){0.f, 0.f, 0.f, 0.f};

    int p = 0;
#pragma unroll 1
    for (int i = 0; i < NTL; ++i) {
        const int kt = kt0 + i;
        __syncthreads();                    // vmcnt(0) drain -> buf[p] DMA complete
        float4 k2q[4];
#pragma unroll
        for (int nb = 0; nb < 4; ++nb)
            k2q[nb] = *(const float4*)&sqb[kt * 64 + nb * 16 + quad * 4];
        if (i + 1 < NTL) {
            const u16* kg = qbase + (size_t)(kt + 1) * 4096;
            const u16* vg = vbase + (size_t)(kt + 1) * 4096;
            const int bb = (p ^ 1) * 4096;
            gl16(kg + ksrc0, Kls + bb + kbase0);
            gl16(kg + ksrc1, Kls + bb + kbase1);
            gl16(vg + vsrc,        Vls + bb + vldsb);
            gl16(vg + 2048 + vsrc, Vls + bb + 2048 + vldsb);
        }

        const u16* Kb = Kls + p * 4096;
        const u16* Vb = Vls + p * 4096;

        bf16x8 bk[4][2];
#pragma unroll
        for (int nb = 0; nb < 4; ++nb) {
            const int rr = (nb * 16 + mcol) * 64;
            bk[nb][0] = *(const bf16x8*)&Kb[rr + ((quad ^ m7)) * 8];
            bk[nb][1] = *(const bf16x8*)&Kb[rr + (((4 + quad) ^ m7)) * 8];
        }

        f32x4 c[4];
#pragma unroll
        for (int nb = 0; nb < 4; ++nb) {
            c[nb] = (f32x4){0.f, 0.f, 0.f, 0.f};
            c[nb] = __builtin_amdgcn_mfma_f32_16x16x32_bf16(bk[nb][0], bq00, c[nb], 0, 0, 0);
            c[nb] = __builtin_amdgcn_mfma_f32_16x16x32_bf16(bk[nb][1], bq01, c[nb], 0, 0, 0);
        }

        bf16x8 bv[4][2];
#pragma unroll
        for (int nb = 0; nb < 4; ++nb) {
            const int rr = (nb * 16 + mcol) * 32 + ((quad ^ mv)) * 8;
            bv[nb][0] = *(const bf16x8*)&Vb[rr];
            bv[nb][1] = *(const bf16x8*)&Vb[2048 + rr];
        }

#pragma unroll
        for (int nb = 0; nb < 4; ++nb) {
            float e[4];
#pragma unroll
            for (int r = 0; r < 4; ++r) {
                const float pre = q2 + ((const float*)&k2q[nb])[r];
                const float d2 = fmaxf(__builtin_fmaf(c[nb][r], -2.0f, pre), 0.0f);
                e[r] = __builtin_amdgcn_exp2f(NEGSL2E * __builtin_amdgcn_sqrtf(d2));
            }
            if (kt == ktm && nb == nbm) {
#pragma unroll
                for (int r = 0; r < 4; ++r)
                    if (quad * 4 + r == mcol) e[r] = 0.0f;   // exp(MASKV) ~ 0
            }
            const u32 p01 = __builtin_amdgcn_perm(__float_as_uint(e[1]), __float_as_uint(e[0]), 0x07060302u);
            const u32 p23 = __builtin_amdgcn_perm(__float_as_uint(e[3]), __float_as_uint(e[2]), 0x07060302u);
            *(uint2*)&Pt[mcol][nb * 16 + quad * 4] = make_uint2(p01, p23);
        }

        const bf16x8 bp00 = *(const bf16x8*)&Pt[mcol][quad * 8];
        const bf16x8 bp01 = *(const bf16x8*)&Pt[mcol][32 + quad * 8];

#pragma unroll
        for (int nb = 0; nb < 4; ++nb) {
            oacc[nb] = __builtin_amdgcn_mfma_f32_16x16x32_bf16(bv[nb][0], bp00, oacc[nb], 0, 0, 0);
            oacc[nb] = __builtin_amdgcn_mfma_f32_16x16x32_bf16(bv[nb][1], bp01, oacc[nb], 0, 0, 0);
        }
        lsum = __builtin_amdgcn_mfma_f32_16x16x32_bf16(ones, bp00, lsum, 0, 0, 0);
        lsum = __builtin_amdgcn_mfma_f32_16x16x32_bf16(ones, bp01, lsum, 0, 0, 0);

        p ^= 1;
    }

    __syncthreads();                        // main loop done; K/V region reusable

    float* Ofin = (float*)sm + wave * (16 * 68);
#pragma unroll
    for (int nb = 0; nb < 4; ++nb)
        *(f32x4*)&Ofin[mcol * 68 + nb * 16 + quad * 4] = oacc[nb];
    if (quad == 0) Ofin[mcol * 68 + 64] = lsum[0];

    {
        const int q = lane >> 2;            // 0..15
        const int d0 = (lane & 3) * 16;     // 0, 16, 32, 48
        const float4 a0 = *(const float4*)&Ofin[q * 68 + d0 + 0];
        const float4 a1 = *(const float4*)&Ofin[q * 68 + d0 + 4];
        const float4 a2 = *(const float4*)&Ofin[q * 68 + d0 + 8];
        const float4 a3 = *(const float4*)&Ofin[q * 68 + d0 + 12];
        const float l = Ofin[q * 68 + 64];
        const int qg = q16 + q;

        if (KS == 2) {
            float* dst = pO + (size_t)kh * 2359296 + ((size_t)bh * NPOS + qg) * 64 + d0;
            *(float4*)&dst[0]  = a0;
            *(float4*)&dst[4]  = a1;
            *(float4*)&dst[8]  = a2;
            *(float4*)&dst[12] = a3;
            if ((lane & 3) == 0)
                pL[(size_t)kh * 36864 + (size_t)bh * NPOS + qg] = l;
        } else {
            const float q2v = sqb[qg];
            const float nd = ndot[(size_t)bh * NPOS + qg];
            const float nk2 = nk2b[h];
            const float d2n = fmaxf(q2v + nk2 - 2.0f * nd, 0.0f);
            const float beta = __expf(-sqrtf(d2n) * SCALE);
            const float ilv = 1.0f / (l + beta);

            const float* nvp = &null_kv[DI + h * 64 + d0];
            const float4 nv0 = *(const float4*)&nvp[0];
            const float4 nv1 = *(const float4*)&nvp[4];
            const float4 nv2 = *(const float4*)&nvp[8];
            const float4 nv3 = *(const float4*)&nvp[12];

            const size_t ob = ((size_t)b * NPOS + qg) * DI + h * 64 + d0;
            float vv[16];
            vv[0]  = (a0.x + beta * nv0.x) * ilv; vv[1]  = (a0.y + beta * nv0.y) * ilv;
            vv[2]  = (a0.z + beta * nv0.z) * ilv; vv[3]  = (a0.w + beta * nv0.w) * ilv;
            vv[4]  = (a1.x + beta * nv1.x) * ilv; vv[5]  = (a1.y + beta * nv1.y) * ilv;
            vv[6]  = (a1.z + beta * nv1.z) * ilv; vv[7]  = (a1.w + beta * nv1.w) * ilv;
            vv[8]  = (a2.x + beta * nv2.x) * ilv; vv[9]  = (a2.y + beta * nv2.y) * ilv;
            vv[10] = (a2.z + beta * nv2.z) * ilv; vv[11] = (a2.w + beta * nv2.w) * ilv;
            vv[12] = (a3.x + beta * nv3.x) * ilv; vv[13] = (a3.y + beta * nv3.y) * ilv;
            vv[14] = (a3.z + beta * nv3.z) * ilv; vv[15] = (a3.w + beta * nv3.w) * ilv;
#pragma unroll
            for (int g = 0; g < 4; ++g) {
                ushort4 hi4, lo4;
                hi4.x = f2bf(vv[g * 4 + 0]); lo4.x = f2bf(vv[g * 4 + 0] - bf2f(hi4.x));
                hi4.y = f2bf(vv[g * 4 + 1]); lo4.y = f2bf(vv[g * 4 + 1] - bf2f(hi4.y));
                hi4.z = f2bf(vv[g * 4 + 2]); lo4.z = f2bf(vv[g * 4 + 2] - bf2f(hi4.z));
                hi4.w = f2bf(vv[g * 4 + 3]); lo4.w = f2bf(vv[g * 4 + 3] - bf2f(hi4.w));
                *(ushort4*)&ih[ob + g * 4] = hi4;
                *(ushort4*)&il[ob + g * 4] = lo4;
            }
        }
    }
}

// ---------------- Kernel 2b: merge k-split partials + beta/normalize -> ih/il ----------------
__global__ __launch_bounds__(256) void k_merge(const float* __restrict__ pO,
                                               const float* __restrict__ pL,
                                               const float* __restrict__ null_kv,
                                               const float* __restrict__ nk2b,
                                               const float* __restrict__ sq,
                                               const float* __restrict__ ndot,
                                               u16* __restrict__ ih,
                                               u16* __restrict__ il) {
    const int gid = blockIdx.x * 256 + (int)threadIdx.x;   // 0..147455
    const int d0 = (gid & 3) * 16;
    const int t2 = gid >> 2;                 // 0..36863
    const int bh = t2 / NPOS;                // 0..15
    const int qg = t2 - bh * NPOS;
    const int b = bh >> 3, h = bh & 7;

    const size_t o0 = ((size_t)bh * NPOS + qg) * 64 + d0;
    const size_t o1 = o0 + 2359296;
    const float4 a0 = *(const float4*)&pO[o0 + 0];
    const float4 a1 = *(const float4*)&pO[o0 + 4];
    const float4 a2 = *(const float4*)&pO[o0 + 8];
    const float4 a3 = *(const float4*)&pO[o0 + 12];
    const float4 c0 = *(const float4*)&pO[o1 + 0];
    const float4 c1 = *(const float4*)&pO[o1 + 4];
    const float4 c2 = *(const float4*)&pO[o1 + 8];
    const float4 c3 = *(const float4*)&pO[o1 + 12];
    const float l = pL[(size_t)bh * NPOS + qg] + pL[36864 + (size_t)bh * NPOS + qg];

    const float q2v = sq[(size_t)bh * NPOS + qg];
    const float nd = ndot[(size_t)bh * NPOS + qg];
    const float nk2 = nk2b[h];
    const float d2n = fmaxf(q2v + nk2 - 2.0f * nd, 0.0f);
    const float beta = __expf(-sqrtf(d2n) * SCALE);
    const float ilv = 1.0f / (l + beta);

    const float* nvp = &null_kv[DI + h * 64 + d0];
    const float4 nv0 = *(const float4*)&nvp[0];
    const float4 nv1 = *(const float4*)&nvp[4];
    const float4 nv2 = *(const float4*)&nvp[8];
    const float4 nv3 = *(const float4*)&nvp[12];

    float vv[16];
    vv[0]  = (a0.x + c0.x + beta * nv0.x) * ilv; vv[1]  = (a0.y + c0.y + beta * nv0.y) * ilv;
    vv[2]  = (a0.z + c0.z + beta * nv0.z) * ilv; vv[3]  = (a0.w + c0.w + beta * nv0.w) * ilv;
    vv[4]  = (a1.x + c1.x + beta * nv1.x) * ilv; vv[5]  = (a1.y + c1.y + beta * nv1.y) * ilv;
    vv[6]  = (a1.z + c1.z + beta * nv1.z) * ilv; vv[7]  = (a1.w + c1.w + beta * nv1.w) * ilv;
    vv[8]  = (a2.x + c2.x + beta * nv2.x) * ilv; vv[9]  = (a2.y + c2.y + beta * nv2.y) * ilv;
    vv[10] = (a2.z + c2.z + beta * nv2.z) * ilv; vv[11] = (a2.w + c2.w + beta * nv2.w) * ilv;
    vv[12] = (a3.x + c3.x + beta * nv3.x) * ilv; vv[13] = (a3.y + c3.y + beta * nv3.y) * ilv;
    vv[14] = (a3.z + c3.z + beta * nv3.z) * ilv; vv[15] = (a3.w + c3.w + beta * nv3.w) * ilv;

    const size_t ob = ((size_t)b * NPOS + qg) * DI + h * 64 + d0;
#pragma unroll
    for (int g = 0; g < 4; ++g) {
        ushort4 hi4, lo4;
        hi4.x = f2bf(vv[g * 4 + 0]); lo4.x = f2bf(vv[g * 4 + 0] - bf2f(hi4.x));
        hi4.y = f2bf(vv[g * 4 + 1]); lo4.y = f2bf(vv[g * 4 + 1] - bf2f(hi4.y));
        hi4.z = f2bf(vv[g * 4 + 2]); lo4.z = f2bf(vv[g * 4 + 2] - bf2f(hi4.z));
        hi4.w = f2bf(vv[g * 4 + 3]); lo4.w = f2bf(vv[g * 4 + 3] - bf2f(hi4.w));
        *(ushort4*)&ih[ob + g * 4] = hi4;
        *(ushort4*)&il[ob + g * 4] = lo4;
    }
}

// ---------------- Kernel 3: output projection, LDS-staged B (shared across waves) ----------------
__global__ __launch_bounds__(256) void k_out(const u16* __restrict__ wo_hi,
                                             const u16* __restrict__ wo_lo,
                                             const u16* __restrict__ ih,
                                             const u16* __restrict__ il,
                                             float* __restrict__ out) {
    const int j0 = blockIdx.x * 32;        // 72 j-tiles of 32 -> 576 blocks
    const int c0 = blockIdx.y * 64;
    const int b  = blockIdx.z;
    const int t  = threadIdx.x;
    const int w = t >> 6, lane = t & 63, mcol = lane & 15, quad = lane >> 4;

    // [buf][hi/lo][32 j][64 k] u16 = 16 KB
    __shared__ __align__(16) u16 Bst[2][2][32][64];

    const u16* ah = wo_hi + (size_t)(c0 + w * 16 + mcol) * 512 + quad * 8;
    const u16* al = wo_lo + (size_t)(c0 + w * 16 + mcol) * 512 + quad * 8;

    const size_t bsrc_row = (size_t)b * NPOS + j0 + w * 8 + (lane >> 3);
    const int bsg = ((lane & 7) ^ (lane >> 3)) * 8;
    const u16* bsrc_h = ih + bsrc_row * 512 + bsg;
    const u16* bsrc_l = il + bsrc_row * 512 + bsg;
    u16* bdst_h = &Bst[0][0][w * 8][0];
    u16* bdst_l = &Bst[0][1][w * 8][0];

    gl16(bsrc_h, bdst_h);                  // phase 0 -> buf 0
    gl16(bsrc_l, bdst_l);

    f32x4 c[2];
    c[0] = (f32x4){0.f, 0.f, 0.f, 0.f};
    c[1] = (f32x4){0.f, 0.f, 0.f, 0.f};

    int p = 0;
#pragma unroll 1
    for (int ph = 0; ph < 8; ++ph) {
        __syncthreads();                   // vmcnt(0) drain -> buf[p] complete
        if (ph + 1 < 8) {
            const int ko = (ph + 1) * 64;
            gl16(bsrc_h + ko, bdst_h + (p ^ 1) * 4096);
            gl16(bsrc_l + ko, bdst_l + (p ^ 1) * 4096);
        }
        const u16* Bb = &Bst[p][0][0][0];
#pragma unroll
        for (int sub = 0; sub < 2; ++sub) {
            const int kc = ph * 2 + sub;
            const bf16x8 A  = *(const bf16x8*)&ah[kc * 32];
            const bf16x8 Al = *(const bf16x8*)&al[kc * 32];
#pragma unroll
            for (int nf = 0; nf < 2; ++nf) {
                const int r = nf * 16 + mcol;
                const int g = (sub * 4 + quad) ^ (r & 7);
                const bf16x8 Bh = *(const bf16x8*)&Bb[r * 64 + g * 8];
                const bf16x8 Bl = *(const bf16x8*)&Bb[2048 + r * 64 + g * 8];
                c[nf] = __builtin_amdgcn_mfma_f32_16x16x32_bf16(A,  Bh, c[nf], 0, 0, 0);
                c[nf] = __builtin_amdgcn_mfma_f32_16x16x32_bf16(A,  Bl, c[nf], 0, 0, 0);
                c[nf] = __builtin_amdgcn_mfma_f32_16x16x32_bf16(Al, Bh, c[nf], 0, 0, 0);
            }
        }
        p ^= 1;
    }
    float* ob = out + ((size_t)b * CC + c0 + w * 16) * NPOS + j0;
#pragma unroll
    for (int nf = 0; nf < 2; ++nf)
#pragma unroll
        for (int r = 0; r < 4; ++r)
            ob[(size_t)(quad * 4 + r) * NPOS + nf * 16 + mcol] = c[nf][r];
}

extern "C" void kernel_launch(void* const* d_in, const int* in_sizes, int n_in,
                              void* d_out, int out_size, void* d_ws, size_t ws_size,
                              hipStream_t stream) {
    const float* fmap    = (const float*)d_in[0];
    const float* gamma   = (const float*)d_in[1];
    const float* w_qk    = (const float*)d_in[2];
    const float* w_v     = (const float*)d_in[3];
    const float* null_kv = (const float*)d_in[4];
    const float* w_out   = (const float*)d_in[5];
    float* out = (float*)d_out;

    u16* ws16 = (u16*)d_ws;
    u16* qkh    = ws16;                     // 16*2304*64  = 2,359,296 u16
    u16* vtb    = qkh + 2359296;            // 16*72*64*32 = 2,359,296
    u16* in_hi  = vtb + 2359296;            // 2*2304*512  = 2,359,296
    u16* in_lo  = in_hi + 2359296;          //               2,359,296
    u16* wo_hi  = in_lo + 2359296;          // 256*512     =   131,072
    u16* wo_lo  = wo_hi + 131072;           //                 131,072
    u16* wqkh   = wo_lo + 131072;           // 512*256     =   131,072
    u16* wvh    = wqkh + 131072;            //                 131,072
    float* sqbuf = (float*)(wvh + 131072);      // 36,864 f32
    float* ndbuf = sqbuf + 36864;               // 36,864
    float* nk2b  = ndbuf + 36864;               // 8
    // base total ~20.2 MB; k-split partials below need +19.2 MB
    float* pOws  = nk2b + 8;                    // 2*16*2304*64 = 4,718,592 f32
    float* pLws  = pOws + 4718592;              // 2*16*2304    =    73,728 f32
    const size_t need_split = (size_t)((char*)(pLws + 73728) - (char*)d_ws);

    hipLaunchKernelGGL(k_prep, dim3(384),       dim3(256), 0, stream,
                       w_qk, w_v, w_out, wqkh, wvh, wo_hi, wo_lo);
    hipLaunchKernelGGL(k_proj, dim3(576),       dim3(256), 0, stream,
                       fmap, gamma, wqkh, wvh, null_kv, qkh, vtb, sqbuf, ndbuf, nk2b);
    if (ws_size >= need_split) {
        hipLaunchKernelGGL(HIP_KERNEL_NAME(k_attn<2>), dim3(1152), dim3(256), 0, stream,
                           qkh, vtb, null_kv, nk2b, sqbuf, ndbuf, in_hi, in_lo, pOws, pLws);
        hipLaunchKernelGGL(k_merge, dim3(576),  dim3(256), 0, stream,
                           pOws, pLws, null_kv, nk2b, sqbuf, ndbuf, in_hi, in_lo);
    } else {
        hipLaunchKernelGGL(HIP_KERNEL_NAME(k_attn<1>), dim3(576), dim3(256), 0, stream,
                           qkh, vtb, null_kv, nk2b, sqbuf, ndbuf, in_hi, in_lo, pOws, pLws);
    }
    hipLaunchKernelGGL(k_out,  dim3(72, 4, 2),  dim3(256), 0, stream,
                       wo_hi, wo_lo, in_hi, in_lo, out);
}